// Round 14
// baseline (666.430 us; speedup 1.0000x reference)
//
#include <hip/hip_runtime.h>
#include <hip/hip_bf16.h>

#define T_TOK 2048
#define H_DIM 2048
#define E_NUM 32
#define I_DIM 768
#define TOPK  4
#define S4    (T_TOK * TOPK)          // 8192 slots (sum of counts is always T*K)

typedef __attribute__((ext_vector_type(8))) short bf16x8;
typedef __attribute__((ext_vector_type(4))) float f32x4;

__device__ __forceinline__ unsigned pk2(float a, float b) {
    __hip_bfloat16 ha = __float2bfloat16(a);
    __hip_bfloat16 hb = __float2bfloat16(b);
    unsigned short ua = *(unsigned short*)&ha;
    unsigned short ub = *(unsigned short*)&hb;
    return (unsigned)ua | ((unsigned)ub << 16);
}

#define MFMA16(a, b, c) __builtin_amdgcn_mfma_f32_16x16x32_bf16(a, b, c, 0, 0, 0)

// ---------------- grid-stride zero ----------------
__global__ __launch_bounds__(256) void zero_kernel(uint4* __restrict__ p, long n16)
{
    long i = (long)blockIdx.x * 256 + threadIdx.x;
    long stride = (long)gridDim.x * 256;
    for (; i < n16; i += stride) p[i] = (uint4){0u, 0u, 0u, 0u};
}

// ---------------- Router ----------------
__global__ __launch_bounds__(64) void router_kernel(
    const float* __restrict__ x, const float* __restrict__ gate_w,
    float* __restrict__ logits_out, int* __restrict__ cnt,
    int* __restrict__ tok_list, float* __restrict__ tok_w,
    int* __restrict__ tok_slots)
{
    const int t = blockIdx.x;
    const int lane = threadIdx.x;
    __shared__ float xs[H_DIM];
    const float4* __restrict__ xv = (const float4*)(x + (size_t)t * H_DIM);
    float4* xsv = (float4*)xs;
#pragma unroll
    for (int i = 0; i < H_DIM / 4 / 64; ++i) xsv[lane + i * 64] = xv[lane + i * 64];
    __syncthreads();

    const int e = lane & 31;
    const int half = lane >> 5;
    const float4* __restrict__ wv = (const float4*)(gate_w + (size_t)e * H_DIM) + half * (H_DIM / 8);
    const float4* __restrict__ xh = ((const float4*)xs) + half * (H_DIM / 8);
    float acc = 0.f;
#pragma unroll 4
    for (int i = 0; i < H_DIM / 8; ++i) {
        float4 w4 = wv[i], x4 = xh[i];
        acc += w4.x * x4.x + w4.y * x4.y + w4.z * x4.z + w4.w * x4.w;
    }
    acc += __shfl_xor(acc, 32, 64);
    if (lane < 32) logits_out[(size_t)t * E_NUM + e] = acc;

    float v = acc;
    float topv[TOPK]; int topi[TOPK];
#pragma unroll
    for (int r = 0; r < TOPK; ++r) {
        float bv = v; int bi = e;
#pragma unroll
        for (int off = 16; off >= 1; off >>= 1) {
            float ov = __shfl_xor(bv, off, 32);
            int   oi = __shfl_xor(bi, off, 32);
            if (ov > bv || (ov == bv && oi < bi)) { bv = ov; bi = oi; }
        }
        topv[r] = bv; topi[r] = bi;
        if (e == bi) v = -1e30f;
    }
    if (lane == 0) {
        float w[TOPK]; float s = 0.f;
#pragma unroll
        for (int r = 0; r < TOPK; ++r) { w[r] = expf(topv[r] - topv[0]); s += w[r]; }
        float inv = 1.f / s;
#pragma unroll
        for (int r = 0; r < TOPK; ++r) {
            int pos = atomicAdd(&cnt[topi[r]], 1);
            tok_list[topi[r] * T_TOK + pos] = t;
            tok_w  [topi[r] * T_TOK + pos] = w[r] * inv;
            tok_slots[t * TOPK + r] = (topi[r] << 12) | pos;
        }
    }
}

__global__ void scan_kernel(const int* __restrict__ cnt, int* __restrict__ slot_base)
{
    if (threadIdx.x == 0) {
        int s = 0;
        for (int e = 0; e < E_NUM; ++e) { slot_base[e] = s; s += cnt[e]; }
        slot_base[E_NUM] = s;
    }
}

// ------- Gather: x -> bf16 K-panels; also slot_w[slot] = router weight -------
__global__ __launch_bounds__(256) void gather_kernel(
    const float* __restrict__ x, const int* __restrict__ cnt,
    const int* __restrict__ slot_base, const int* __restrict__ tok_list,
    const float* __restrict__ tok_w, unsigned short* __restrict__ xg_t,
    float* __restrict__ slot_w)
{
    const int e = blockIdx.x;
    const int count = cnt[e];
    const int m0 = blockIdx.y * 8;
    if (m0 >= count) return;
    const int s8   = threadIdx.x >> 5;
    const int kc31 = threadIdx.x & 31;
    const int m = m0 + s8;
    if (m >= count) return;
    const int tok  = tok_list[e * T_TOK + m];
    const int slot = slot_base[e] + m;
    if (kc31 == 0) slot_w[slot] = tok_w[e * T_TOK + m];
    const float* __restrict__ src = x + (size_t)tok * H_DIM;
#pragma unroll
    for (int kcq = 0; kcq < 8; ++kcq) {
        const int kc = kcq * 32 + kc31;
        float4 a = *(const float4*)(src + kc * 8);
        float4 b = *(const float4*)(src + kc * 8 + 4);
        uint4 o;
        o.x = pk2(a.x, a.y); o.y = pk2(a.z, a.w);
        o.z = pk2(b.x, b.y); o.w = pk2(b.z, b.w);
        *(uint4*)(xg_t + ((size_t)kc * S4 + slot) * 8) = o;
    }
}

// -------- gate_up partial GEMM (K-split x4) -> f32 atomic partials ---------
// tile 256(M) x 32(g)+32(u); 4 chunks of K=128 per block. grid (32e,24nt,8mt*4ks).
__global__ __launch_bounds__(512, 4) void gu_partial(
    const unsigned short* __restrict__ xg_t, const float* __restrict__ gup_w,
    const int* __restrict__ cnt, const int* __restrict__ slot_base,
    float* __restrict__ gacc, float* __restrict__ uacc)
{
    const int e  = blockIdx.x;
    const int nt = blockIdx.y;
    const int mt = blockIdx.z >> 2;
    const int ks = blockIdx.z & 3;
    const int count = cnt[e];
    if (mt * 256 >= count) return;
    const int tid  = threadIdx.x;
    const int lane = tid & 63;
    const int w    = tid >> 6;
    const int base = slot_base[e];
    const int l16  = lane & 15, lg = lane >> 4;

    __shared__ unsigned short Bls[2][2][16 * 32 * 8];  // [buf][half][kk16][n32][8] 32KB

    int m0 = mt * 256 + w * 32 + l16;      if (m0 >= count) m0 = count - 1;
    int m1 = mt * 256 + w * 32 + 16 + l16; if (m1 >= count) m1 = count - 1;
    const unsigned short* a0b = xg_t + (size_t)(base + m0) * 8;
    const unsigned short* a1b = xg_t + (size_t)(base + m1) * 8;

    const int bhalf = tid >> 8;
    const int sub   = (tid >> 7) & 1;
    const int t7    = tid & 127;
    const int kb    = (t7 >> 3) * 2;
    const int n4    = (t7 & 7) * 4;
    const int k8    = kb & 7;
    const int kbh   = kb >> 3;
    const float* __restrict__ bbase =
        gup_w + ((size_t)e * H_DIM + kb) * (2 * I_DIM) + (size_t)bhalf * I_DIM + nt * 32 + n4;

    float4 sv0[2], sv1[2];

#define GU_LOAD(C) do { _Pragma("unroll") for (int q2 = 0; q2 < 2; ++q2) { \
        const int q = sub + q2 * 2; \
        const float* s_ = bbase + (size_t)((C) * 128 + q * 32) * (2 * I_DIM); \
        sv0[q2] = *(const float4*)s_; \
        sv1[q2] = *(const float4*)(s_ + 2 * I_DIM); } } while (0)
#define GU_WRITE(BUF) do { _Pragma("unroll") for (int q2 = 0; q2 < 2; ++q2) { \
        const int q = sub + q2 * 2; \
        unsigned short* bw_ = &Bls[BUF][bhalf][((q * 4 + kbh) * 32) * 8]; \
        float p0[4] = {sv0[q2].x, sv0[q2].y, sv0[q2].z, sv0[q2].w}; \
        float p1[4] = {sv1[q2].x, sv1[q2].y, sv1[q2].z, sv1[q2].w}; \
        _Pragma("unroll") for (int j = 0; j < 4; ++j) \
            *(unsigned*)&bw_[(n4 + j) * 8 + k8] = pk2(p0[j], p1[j]); } } while (0)

    f32x4 accg[2][2], accu[2][2];
#pragma unroll
    for (int i = 0; i < 2; ++i)
#pragma unroll
        for (int f = 0; f < 2; ++f) { accg[i][f] = {0.f,0.f,0.f,0.f}; accu[i][f] = {0.f,0.f,0.f,0.f}; }

    const int c0 = ks * 4;
    GU_LOAD(c0);
    GU_WRITE(0);

    for (int cc = 0; cc < 4; ++cc) {
        const int c = c0 + cc;
        const int buf = cc & 1;
        __syncthreads();
        if (cc + 1 < 4) GU_LOAD(c + 1);
#pragma unroll
        for (int s = 0; s < 4; ++s) {
            const size_t aoff = (size_t)(c * 16 + s * 4 + lg) * (S4 * 8);
            bf16x8 a0 = *(const bf16x8*)(a0b + aoff);
            bf16x8 a1 = *(const bf16x8*)(a1b + aoff);
            const unsigned short* bg_ = &Bls[buf][0][((s * 4 + lg) * 32 + l16) * 8];
            const unsigned short* bu_ = &Bls[buf][1][((s * 4 + lg) * 32 + l16) * 8];
            bf16x8 g0 = *(const bf16x8*)(bg_);
            bf16x8 g1 = *(const bf16x8*)(bg_ + 128);
            bf16x8 u0 = *(const bf16x8*)(bu_);
            bf16x8 u1 = *(const bf16x8*)(bu_ + 128);
            accg[0][0] = MFMA16(a0, g0, accg[0][0]);
            accg[0][1] = MFMA16(a0, g1, accg[0][1]);
            accu[0][0] = MFMA16(a0, u0, accu[0][0]);
            accu[0][1] = MFMA16(a0, u1, accu[0][1]);
            accg[1][0] = MFMA16(a1, g0, accg[1][0]);
            accg[1][1] = MFMA16(a1, g1, accg[1][1]);
            accu[1][0] = MFMA16(a1, u0, accu[1][0]);
            accu[1][1] = MFMA16(a1, u1, accu[1][1]);
        }
        if (cc + 1 < 4) GU_WRITE(buf ^ 1);
    }
#undef GU_LOAD
#undef GU_WRITE

#pragma unroll
    for (int i = 0; i < 2; ++i) {
        const int mloc = w * 32 + i * 16 + lg * 4;
#pragma unroll
        for (int r = 0; r < 4; ++r) {
            const int mrow = mt * 256 + mloc + r;
            if (mrow < count) {
                const size_t slot = (size_t)(base + mrow);
#pragma unroll
                for (int f = 0; f < 2; ++f) {
                    const int col = nt * 32 + f * 16 + l16;
                    atomicAdd(&gacc[slot * I_DIM + col], accg[i][f][r]);
                    atomicAdd(&uacc[slot * I_DIM + col], accu[i][f][r]);
                }
            }
        }
    }
}

// -------- silu_h: h = wgt * u * silu(g) -> h_t panels (bf16) ----------------
// block 256 = 2 slots x 128 threads (96 active each). grid S4/2.
__global__ __launch_bounds__(256) void silu_h(
    const float* __restrict__ gacc, const float* __restrict__ uacc,
    const float* __restrict__ slot_w, unsigned short* __restrict__ h_t)
{
    const int slot = blockIdx.x * 2 + (threadIdx.x >> 7);
    const int j = threadIdx.x & 127;
    if (j >= 96) return;
    const float wgt = slot_w[slot];
    const float* gp = gacc + (size_t)slot * I_DIM + j * 8;
    const float* up = uacc + (size_t)slot * I_DIM + j * 8;
    float4 g0 = *(const float4*)gp, g1 = *(const float4*)(gp + 4);
    float4 u0 = *(const float4*)up, u1 = *(const float4*)(up + 4);
    float gv[8] = {g0.x, g0.y, g0.z, g0.w, g1.x, g1.y, g1.z, g1.w};
    float uv[8] = {u0.x, u0.y, u0.z, u0.w, u1.x, u1.y, u1.z, u1.w};
    float hv[8];
#pragma unroll
    for (int k = 0; k < 8; ++k) {
        float g = gv[k];
        hv[k] = wgt * uv[k] * (g / (1.f + expf(-g)));
    }
    uint4 o;
    o.x = pk2(hv[0], hv[1]); o.y = pk2(hv[2], hv[3]);
    o.z = pk2(hv[4], hv[5]); o.w = pk2(hv[6], hv[7]);
    *(uint4*)(h_t + ((size_t)j * S4 + slot) * 8) = o;
}

// -------- down partial GEMM (K-split x3) -> f32 atomic into ods -------------
// tile 256(M) x 64(N); 2 chunks of K=128 per block. grid (32e,32nt,8mt*3ks).
__global__ __launch_bounds__(512, 4) void dn_partial(
    const unsigned short* __restrict__ h_t, const float* __restrict__ down_w,
    const int* __restrict__ cnt, const int* __restrict__ slot_base,
    float* __restrict__ ods)
{
    const int e  = blockIdx.x;
    const int nt = blockIdx.y;
    const int mt = blockIdx.z / 3;
    const int ks = blockIdx.z % 3;
    const int count = cnt[e];
    if (mt * 256 >= count) return;
    const int tid  = threadIdx.x;
    const int lane = tid & 63;
    const int w    = tid >> 6;
    const int base = slot_base[e];
    const int l16  = lane & 15, lg = lane >> 4;

    __shared__ unsigned short Bls[2][16 * 64 * 8];   // [buf][kk16][n64][8] 32KB

    int m0 = mt * 256 + w * 32 + l16;      if (m0 >= count) m0 = count - 1;
    int m1 = mt * 256 + w * 32 + 16 + l16; if (m1 >= count) m1 = count - 1;
    const unsigned short* a0b = h_t + (size_t)(base + m0) * 8;
    const unsigned short* a1b = h_t + (size_t)(base + m1) * 8;

    const int sub = tid >> 8;
    const int t8  = tid & 255;
    const int kb  = (t8 >> 4) * 2;
    const int n4  = (t8 & 15) * 4;
    const int k8  = kb & 7;
    const int kbh = kb >> 3;
    const float* __restrict__ bbase =
        down_w + ((size_t)e * I_DIM + kb) * H_DIM + nt * 64 + n4;

    float4 sv0[2], sv1[2];

#define DN_LOAD(C) do { _Pragma("unroll") for (int q2 = 0; q2 < 2; ++q2) { \
        const int q = sub + q2 * 2; \
        const float* s_ = bbase + (size_t)((C) * 128 + q * 32) * H_DIM; \
        sv0[q2] = *(const float4*)s_; \
        sv1[q2] = *(const float4*)(s_ + H_DIM); } } while (0)
#define DN_WRITE(BUF) do { _Pragma("unroll") for (int q2 = 0; q2 < 2; ++q2) { \
        const int q = sub + q2 * 2; \
        unsigned short* bw_ = &Bls[BUF][((q * 4 + kbh) * 64) * 8]; \
        float p0[4] = {sv0[q2].x, sv0[q2].y, sv0[q2].z, sv0[q2].w}; \
        float p1[4] = {sv1[q2].x, sv1[q2].y, sv1[q2].z, sv1[q2].w}; \
        _Pragma("unroll") for (int j = 0; j < 4; ++j) \
            *(unsigned*)&bw_[(n4 + j) * 8 + k8] = pk2(p0[j], p1[j]); } } while (0)

    f32x4 acc[2][4];
#pragma unroll
    for (int i = 0; i < 2; ++i)
#pragma unroll
        for (int f = 0; f < 4; ++f) acc[i][f] = {0.f,0.f,0.f,0.f};

    const int c0 = ks * 2;
    DN_LOAD(c0);
    DN_WRITE(0);

    for (int cc = 0; cc < 2; ++cc) {
        const int c = c0 + cc;
        const int buf = cc & 1;
        __syncthreads();
        if (cc + 1 < 2) DN_LOAD(c + 1);
#pragma unroll
        for (int s = 0; s < 4; ++s) {
            const size_t aoff = (size_t)(c * 16 + s * 4 + lg) * (S4 * 8);
            bf16x8 a0 = *(const bf16x8*)(a0b + aoff);
            bf16x8 a1 = *(const bf16x8*)(a1b + aoff);
            const unsigned short* bf_ = &Bls[buf][((s * 4 + lg) * 64 + l16) * 8];
            bf16x8 b0 = *(const bf16x8*)(bf_);
            bf16x8 b1 = *(const bf16x8*)(bf_ + 128);
            bf16x8 b2 = *(const bf16x8*)(bf_ + 256);
            bf16x8 b3 = *(const bf16x8*)(bf_ + 384);
            acc[0][0] = MFMA16(a0, b0, acc[0][0]);
            acc[0][1] = MFMA16(a0, b1, acc[0][1]);
            acc[0][2] = MFMA16(a0, b2, acc[0][2]);
            acc[0][3] = MFMA16(a0, b3, acc[0][3]);
            acc[1][0] = MFMA16(a1, b0, acc[1][0]);
            acc[1][1] = MFMA16(a1, b1, acc[1][1]);
            acc[1][2] = MFMA16(a1, b2, acc[1][2]);
            acc[1][3] = MFMA16(a1, b3, acc[1][3]);
        }
        if (cc + 1 < 2) DN_WRITE(buf ^ 1);
    }
#undef DN_LOAD
#undef DN_WRITE

#pragma unroll
    for (int i = 0; i < 2; ++i) {
        const int mloc = w * 32 + i * 16 + lg * 4;
#pragma unroll
        for (int r = 0; r < 4; ++r) {
            const int mrow = mt * 256 + mloc + r;
            if (mrow < count) {
                float* orow = ods + (size_t)(base + mrow) * H_DIM + nt * 64;
#pragma unroll
                for (int f = 0; f < 4; ++f)
                    atomicAdd(&orow[f * 16 + l16], acc[i][f][r]);
            }
        }
    }
}

// ---------------- combine: out[t] = sum of t's 4 slot rows ----------------
__global__ __launch_bounds__(256) void combine_kernel(
    const float* __restrict__ ods, const int* __restrict__ tok_slots,
    const int* __restrict__ slot_base, float* __restrict__ out)
{
    const int t = blockIdx.x;
    const int c0 = threadIdx.x * 8;
    const float* rows[TOPK];
#pragma unroll
    for (int r = 0; r < TOPK; ++r) {
        const int pk = tok_slots[t * TOPK + r];
        const int e = pk >> 12, pos = pk & 4095;
        rows[r] = ods + (size_t)(slot_base[e] + pos) * H_DIM + c0;
    }
    float4 a0 = {0.f,0.f,0.f,0.f}, a1 = {0.f,0.f,0.f,0.f};
#pragma unroll
    for (int r = 0; r < TOPK; ++r) {
        float4 v0 = *(const float4*)(rows[r]);
        float4 v1 = *(const float4*)(rows[r] + 4);
        a0.x += v0.x; a0.y += v0.y; a0.z += v0.z; a0.w += v0.w;
        a1.x += v1.x; a1.y += v1.y; a1.z += v1.z; a1.w += v1.w;
    }
    float* o = out + (size_t)t * H_DIM + c0;
    *(float4*)o = a0;
    *(float4*)(o + 4) = a1;
}

extern "C" void kernel_launch(void* const* d_in, const int* in_sizes, int n_in,
                              void* d_out, int out_size, void* d_ws, size_t ws_size,
                              hipStream_t stream) {
    const float* x      = (const float*)d_in[0];
    const float* gate_w = (const float*)d_in[1];
    const float* gup_w  = (const float*)d_in[2];
    const float* down_w = (const float*)d_in[3];
    float* out    = (float*)d_out;

    char* wsp = (char*)d_ws;
    int*   cnt       = (int*)(wsp);
    int*   slot_base = (int*)(wsp + 256);
    int*   tok_list  = (int*)(wsp + 4096);
    float* tok_w     = (float*)(wsp + 4096 + (size_t)E_NUM * T_TOK * 4);
    int*   tok_slots = (int*)(wsp + (768u << 10));     // 32 KB
    float* slot_w    = (float*)(wsp + (832u << 10));   // 32 KB

    size_t off = (size_t)1 << 20;
    unsigned short* xg_t = (unsigned short*)(wsp + off); off += (size_t)S4 * H_DIM * 2;  // 33.6MB
    unsigned short* h_t  = (unsigned short*)(wsp + off); off += (size_t)S4 * I_DIM * 2;  // 12.6MB
    // contiguous zero region: gacc, uacc, ods
    float* gacc = (float*)(wsp + off);
    float* uacc = gacc + (size_t)S4 * I_DIM;            // 25.2MB each
    float* ods  = uacc + (size_t)S4 * I_DIM;            // 67MB
    const long zero16 = ((size_t)S4 * I_DIM * 2 + (size_t)S4 * H_DIM) / 4; // uint4 count

    hipMemsetAsync(cnt, 0, 256, stream);
    zero_kernel<<<4096, 256, 0, stream>>>((uint4*)gacc, zero16);

    router_kernel<<<T_TOK, 64, 0, stream>>>(x, gate_w, out + (size_t)T_TOK * H_DIM,
                                            cnt, tok_list, tok_w, tok_slots);
    scan_kernel<<<1, 64, 0, stream>>>(cnt, slot_base);
    gather_kernel<<<dim3(E_NUM, 256), 256, 0, stream>>>(x, cnt, slot_base, tok_list,
                                                        tok_w, xg_t, slot_w);
    gu_partial<<<dim3(E_NUM, 24, 32), 512, 0, stream>>>(
        xg_t, gup_w, cnt, slot_base, gacc, uacc);
    silu_h<<<S4 / 2, 256, 0, stream>>>(gacc, uacc, slot_w, h_t);
    dn_partial<<<dim3(E_NUM, 32, 24), 512, 0, stream>>>(
        h_t, down_w, cnt, slot_base, ods);
    combine_kernel<<<T_TOK, 256, 0, stream>>>(ods, tok_slots, slot_base, out);
}

// Round 15
// 436.929 us; speedup vs baseline: 1.5253x; 1.5253x over previous
//
#include <hip/hip_runtime.h>
#include <hip/hip_bf16.h>

#define T_TOK 2048
#define H_DIM 2048
#define E_NUM 32
#define I_DIM 768
#define TOPK  4
#define S4    (T_TOK * TOPK)          // 8192 slots

typedef __attribute__((ext_vector_type(8))) short bf16x8;
typedef __attribute__((ext_vector_type(4))) float f32x4;

__device__ __forceinline__ unsigned pk2(float a, float b) {
    __hip_bfloat16 ha = __float2bfloat16(a);
    __hip_bfloat16 hb = __float2bfloat16(b);
    unsigned short ua = *(unsigned short*)&ha;
    unsigned short ub = *(unsigned short*)&hb;
    return (unsigned)ua | ((unsigned)ub << 16);
}

#define MFMA16(a, b, c) __builtin_amdgcn_mfma_f32_16x16x32_bf16(a, b, c, 0, 0, 0)

// ---------------- Router ----------------
__global__ __launch_bounds__(64) void router_kernel(
    const float* __restrict__ x, const float* __restrict__ gate_w,
    float* __restrict__ logits_out, int* __restrict__ cnt,
    int* __restrict__ tok_list, float* __restrict__ tok_w,
    int* __restrict__ tok_slots)
{
    const int t = blockIdx.x;
    const int lane = threadIdx.x;
    __shared__ float xs[H_DIM];
    const float4* __restrict__ xv = (const float4*)(x + (size_t)t * H_DIM);
    float4* xsv = (float4*)xs;
#pragma unroll
    for (int i = 0; i < H_DIM / 4 / 64; ++i) xsv[lane + i * 64] = xv[lane + i * 64];
    __syncthreads();

    const int e = lane & 31;
    const int half = lane >> 5;
    const float4* __restrict__ wv = (const float4*)(gate_w + (size_t)e * H_DIM) + half * (H_DIM / 8);
    const float4* __restrict__ xh = ((const float4*)xs) + half * (H_DIM / 8);
    float acc = 0.f;
#pragma unroll 4
    for (int i = 0; i < H_DIM / 8; ++i) {
        float4 w4 = wv[i], x4 = xh[i];
        acc += w4.x * x4.x + w4.y * x4.y + w4.z * x4.z + w4.w * x4.w;
    }
    acc += __shfl_xor(acc, 32, 64);
    if (lane < 32) logits_out[(size_t)t * E_NUM + e] = acc;

    float v = acc;
    float topv[TOPK]; int topi[TOPK];
#pragma unroll
    for (int r = 0; r < TOPK; ++r) {
        float bv = v; int bi = e;
#pragma unroll
        for (int off = 16; off >= 1; off >>= 1) {
            float ov = __shfl_xor(bv, off, 32);
            int   oi = __shfl_xor(bi, off, 32);
            if (ov > bv || (ov == bv && oi < bi)) { bv = ov; bi = oi; }
        }
        topv[r] = bv; topi[r] = bi;
        if (e == bi) v = -1e30f;
    }
    if (lane == 0) {
        float w[TOPK]; float s = 0.f;
#pragma unroll
        for (int r = 0; r < TOPK; ++r) { w[r] = expf(topv[r] - topv[0]); s += w[r]; }
        float inv = 1.f / s;
#pragma unroll
        for (int r = 0; r < TOPK; ++r) {
            int pos = atomicAdd(&cnt[topi[r]], 1);
            tok_list[topi[r] * T_TOK + pos] = t;
            tok_w  [topi[r] * T_TOK + pos] = w[r] * inv;
            tok_slots[t * TOPK + r] = (topi[r] << 12) | pos;
        }
    }
}

__global__ void scan_kernel(const int* __restrict__ cnt, int* __restrict__ slot_base)
{
    if (threadIdx.x == 0) {
        int s = 0;
        for (int e = 0; e < E_NUM; ++e) { slot_base[e] = s; s += cnt[e]; }
        slot_base[E_NUM] = s;
    }
}

// ------- Gather tokens per expert, convert x -> bf16 in K-PANEL layout -------
__global__ __launch_bounds__(256) void gather_kernel(
    const float* __restrict__ x, const int* __restrict__ cnt,
    const int* __restrict__ slot_base, const int* __restrict__ tok_list,
    unsigned short* __restrict__ xg_t)
{
    const int e = blockIdx.x;
    const int count = cnt[e];
    const int m0 = blockIdx.y * 8;
    if (m0 >= count) return;
    const int s8   = threadIdx.x >> 5;
    const int kc31 = threadIdx.x & 31;
    const int m = m0 + s8;
    if (m >= count) return;
    const int tok  = tok_list[e * T_TOK + m];
    const int slot = slot_base[e] + m;
    const float* __restrict__ src = x + (size_t)tok * H_DIM;
#pragma unroll
    for (int kcq = 0; kcq < 8; ++kcq) {
        const int kc = kcq * 32 + kc31;
        float4 a = *(const float4*)(src + kc * 8);
        float4 b = *(const float4*)(src + kc * 8 + 4);
        uint4 o;
        o.x = pk2(a.x, a.y); o.y = pk2(a.z, a.w);
        o.z = pk2(b.x, b.y); o.w = pk2(b.z, b.w);
        *(uint4*)(xg_t + ((size_t)kc * S4 + slot) * 8) = o;
    }
}

// ---------------- gate_up MFMA + silu + weight-scale -> h_t (panel bf16) -----
// tile 256(M) x 32(g)+32(u); A chunk-hoisted into registers (8 concurrent
// loads/chunk instead of 4 serial load->MFMA chains); B per-128K chunk in LDS.
#define GU_NC (H_DIM / 128)   // 16 chunks
__global__ __launch_bounds__(512, 2) void gateup_mfma(
    const unsigned short* __restrict__ xg_t, const float* __restrict__ gup_w,
    const int* __restrict__ cnt, const int* __restrict__ slot_base,
    const float* __restrict__ tok_w, unsigned short* __restrict__ h_t)
{
    const int e  = blockIdx.x;
    const int nt = blockIdx.y;
    const int mt = blockIdx.z;
    const int count = cnt[e];
    if (mt * 256 >= count) return;
    const int tid  = threadIdx.x;
    const int lane = tid & 63;
    const int w    = tid >> 6;
    const int base = slot_base[e];
    const int l16  = lane & 15, lg = lane >> 4;

    __shared__ unsigned short Bls[2][2][16 * 32 * 8];  // [buf][half][kc16][n32][8] 32KB
    __shared__ float wls[256];                         // 1KB

    if (tid < 256) {
        int m = mt * 256 + tid; if (m >= count) m = count - 1;
        wls[tid] = tok_w[e * T_TOK + m];
    }

    int m0 = mt * 256 + w * 32 + l16;      if (m0 >= count) m0 = count - 1;
    int m1 = mt * 256 + w * 32 + 16 + l16; if (m1 >= count) m1 = count - 1;
    const unsigned short* a0b = xg_t + (size_t)(base + m0) * 8;
    const unsigned short* a1b = xg_t + (size_t)(base + m1) * 8;

    const int bhalf = tid >> 8;
    const int sub   = (tid >> 7) & 1;
    const int t7    = tid & 127;
    const int kb    = (t7 >> 3) * 2;
    const int n4    = (t7 & 7) * 4;
    const int k8    = kb & 7;
    const int kbh   = kb >> 3;
    const float* __restrict__ bbase =
        gup_w + ((size_t)e * H_DIM + kb) * (2 * I_DIM) + (size_t)bhalf * I_DIM + nt * 32 + n4;

    float4 sv0[2], sv1[2];
    bf16x8 aR[8];   // chunk A block: [s]=row0, [4+s]=row1 — static indexing only

#define GU_ALOAD(C) do { _Pragma("unroll") for (int s = 0; s < 4; ++s) { \
        const size_t ao_ = (size_t)((C) * 16 + s * 4 + lg) * (S4 * 8); \
        aR[s]     = *(const bf16x8*)(a0b + ao_); \
        aR[4 + s] = *(const bf16x8*)(a1b + ao_); } } while (0)
#define GU_LOAD(C) do { _Pragma("unroll") for (int q2 = 0; q2 < 2; ++q2) { \
        const int q = sub + q2 * 2; \
        const float* s_ = bbase + (size_t)((C) * 128 + q * 32) * (2 * I_DIM); \
        sv0[q2] = *(const float4*)s_; \
        sv1[q2] = *(const float4*)(s_ + 2 * I_DIM); } } while (0)
#define GU_WRITE(BUF) do { _Pragma("unroll") for (int q2 = 0; q2 < 2; ++q2) { \
        const int q = sub + q2 * 2; \
        unsigned short* bw_ = &Bls[BUF][bhalf][((q * 4 + kbh) * 32) * 8]; \
        float p0[4] = {sv0[q2].x, sv0[q2].y, sv0[q2].z, sv0[q2].w}; \
        float p1[4] = {sv1[q2].x, sv1[q2].y, sv1[q2].z, sv1[q2].w}; \
        _Pragma("unroll") for (int j = 0; j < 4; ++j) \
            *(unsigned*)&bw_[(n4 + j) * 8 + k8] = pk2(p0[j], p1[j]); } } while (0)

    f32x4 accg[2][2], accu[2][2];
#pragma unroll
    for (int i = 0; i < 2; ++i)
#pragma unroll
        for (int f = 0; f < 2; ++f) { accg[i][f] = {0.f,0.f,0.f,0.f}; accu[i][f] = {0.f,0.f,0.f,0.f}; }

    GU_LOAD(0);
    GU_WRITE(0);

    for (int c = 0; c < GU_NC; ++c) {
        const int buf = c & 1;
        __syncthreads();                     // Bls[buf] published for chunk c
        GU_ALOAD(c);                         // 8 concurrent A loads for this chunk
        if (c + 1 < GU_NC) GU_LOAD(c + 1);   // B regs for next chunk (issue-early)
#pragma unroll
        for (int s = 0; s < 4; ++s) {
            bf16x8 a0 = aR[s];
            bf16x8 a1 = aR[4 + s];
            const unsigned short* bg_ = &Bls[buf][0][((s * 4 + lg) * 32 + l16) * 8];
            const unsigned short* bu_ = &Bls[buf][1][((s * 4 + lg) * 32 + l16) * 8];
            bf16x8 g0 = *(const bf16x8*)(bg_);
            bf16x8 g1 = *(const bf16x8*)(bg_ + 128);
            bf16x8 u0 = *(const bf16x8*)(bu_);
            bf16x8 u1 = *(const bf16x8*)(bu_ + 128);
            accg[0][0] = MFMA16(a0, g0, accg[0][0]);
            accg[0][1] = MFMA16(a0, g1, accg[0][1]);
            accu[0][0] = MFMA16(a0, u0, accu[0][0]);
            accu[0][1] = MFMA16(a0, u1, accu[0][1]);
            accg[1][0] = MFMA16(a1, g0, accg[1][0]);
            accg[1][1] = MFMA16(a1, g1, accg[1][1]);
            accu[1][0] = MFMA16(a1, u0, accu[1][0]);
            accu[1][1] = MFMA16(a1, u1, accu[1][1]);
        }
        if (c + 1 < GU_NC) GU_WRITE(buf ^ 1);  // write-late (loads landed under MFMAs)
    }
#undef GU_ALOAD
#undef GU_LOAD
#undef GU_WRITE

#pragma unroll
    for (int i = 0; i < 2; ++i) {
        const int mloc = w * 32 + i * 16 + lg * 4;
#pragma unroll
        for (int r = 0; r < 4; ++r) {
            const int mrow = mt * 256 + mloc + r;
            if (mrow < count) {
                const float wgt = wls[mloc + r];
                const size_t slot = (size_t)(base + mrow);
#pragma unroll
                for (int f = 0; f < 2; ++f) {
                    const int col = nt * 32 + f * 16 + l16;
                    float g = accg[i][f][r], u = accu[i][f][r];
                    float sv = g / (1.f + expf(-g));
                    __hip_bfloat16 hb = __float2bfloat16(wgt * u * sv);
                    h_t[((size_t)(col >> 3) * S4 + slot) * 8 + (col & 7)] = *(unsigned short*)&hb;
                }
            }
        }
    }
}

// ---------------- down MFMA -> slot-major f32 rows (no atomics) ----------------
#define DN_NC (I_DIM / 128)   // 6 chunks
__global__ __launch_bounds__(512, 2) void down_mfma(
    const unsigned short* __restrict__ h_t, const float* __restrict__ down_w,
    const int* __restrict__ cnt, const int* __restrict__ slot_base,
    float* __restrict__ ods)
{
    const int e  = blockIdx.x;
    const int nt = blockIdx.y;
    const int mt = blockIdx.z;
    const int count = cnt[e];
    if (mt * 256 >= count) return;
    const int tid  = threadIdx.x;
    const int lane = tid & 63;
    const int w    = tid >> 6;
    const int base = slot_base[e];
    const int l16  = lane & 15, lg = lane >> 4;

    __shared__ unsigned short Bls[2][16 * 64 * 8];   // [buf][kc16][n64][8] 32KB

    int m0 = mt * 256 + w * 32 + l16;      if (m0 >= count) m0 = count - 1;
    int m1 = mt * 256 + w * 32 + 16 + l16; if (m1 >= count) m1 = count - 1;
    const unsigned short* a0b = h_t + (size_t)(base + m0) * 8;
    const unsigned short* a1b = h_t + (size_t)(base + m1) * 8;

    const int sub = tid >> 8;
    const int t8  = tid & 255;
    const int kb  = (t8 >> 4) * 2;
    const int n4  = (t8 & 15) * 4;
    const int k8  = kb & 7;
    const int kbh = kb >> 3;
    const float* __restrict__ bbase =
        down_w + ((size_t)e * I_DIM + kb) * H_DIM + nt * 64 + n4;

    float4 sv0[2], sv1[2];
    bf16x8 aR[8];

#define DN_ALOAD(C) do { _Pragma("unroll") for (int s = 0; s < 4; ++s) { \
        const size_t ao_ = (size_t)((C) * 16 + s * 4 + lg) * (S4 * 8); \
        aR[s]     = *(const bf16x8*)(a0b + ao_); \
        aR[4 + s] = *(const bf16x8*)(a1b + ao_); } } while (0)
#define DN_LOAD(C) do { _Pragma("unroll") for (int q2 = 0; q2 < 2; ++q2) { \
        const int q = sub + q2 * 2; \
        const float* s_ = bbase + (size_t)((C) * 128 + q * 32) * H_DIM; \
        sv0[q2] = *(const float4*)s_; \
        sv1[q2] = *(const float4*)(s_ + H_DIM); } } while (0)
#define DN_WRITE(BUF) do { _Pragma("unroll") for (int q2 = 0; q2 < 2; ++q2) { \
        const int q = sub + q2 * 2; \
        unsigned short* bw_ = &Bls[BUF][((q * 4 + kbh) * 64) * 8]; \
        float p0[4] = {sv0[q2].x, sv0[q2].y, sv0[q2].z, sv0[q2].w}; \
        float p1[4] = {sv1[q2].x, sv1[q2].y, sv1[q2].z, sv1[q2].w}; \
        _Pragma("unroll") for (int j = 0; j < 4; ++j) \
            *(unsigned*)&bw_[(n4 + j) * 8 + k8] = pk2(p0[j], p1[j]); } } while (0)

    f32x4 acc[2][4];
#pragma unroll
    for (int i = 0; i < 2; ++i)
#pragma unroll
        for (int f = 0; f < 4; ++f) acc[i][f] = {0.f,0.f,0.f,0.f};

    DN_LOAD(0);
    DN_WRITE(0);

    for (int c = 0; c < DN_NC; ++c) {
        const int buf = c & 1;
        __syncthreads();
        DN_ALOAD(c);
        if (c + 1 < DN_NC) DN_LOAD(c + 1);
#pragma unroll
        for (int s = 0; s < 4; ++s) {
            bf16x8 a0 = aR[s];
            bf16x8 a1 = aR[4 + s];
            const unsigned short* bf_ = &Bls[buf][((s * 4 + lg) * 64 + l16) * 8];
            bf16x8 b0 = *(const bf16x8*)(bf_);
            bf16x8 b1 = *(const bf16x8*)(bf_ + 128);
            bf16x8 b2 = *(const bf16x8*)(bf_ + 256);
            bf16x8 b3 = *(const bf16x8*)(bf_ + 384);
            acc[0][0] = MFMA16(a0, b0, acc[0][0]);
            acc[0][1] = MFMA16(a0, b1, acc[0][1]);
            acc[0][2] = MFMA16(a0, b2, acc[0][2]);
            acc[0][3] = MFMA16(a0, b3, acc[0][3]);
            acc[1][0] = MFMA16(a1, b0, acc[1][0]);
            acc[1][1] = MFMA16(a1, b1, acc[1][1]);
            acc[1][2] = MFMA16(a1, b2, acc[1][2]);
            acc[1][3] = MFMA16(a1, b3, acc[1][3]);
        }
        if (c + 1 < DN_NC) DN_WRITE(buf ^ 1);
    }
#undef DN_ALOAD
#undef DN_LOAD
#undef DN_WRITE

#pragma unroll
    for (int i = 0; i < 2; ++i) {
        const int mloc = w * 32 + i * 16 + lg * 4;
#pragma unroll
        for (int r = 0; r < 4; ++r) {
            const int mrow = mt * 256 + mloc + r;
            if (mrow < count) {
                float* orow = ods + (size_t)(base + mrow) * H_DIM + nt * 64;
#pragma unroll
                for (int f = 0; f < 4; ++f)
                    orow[f * 16 + l16] = acc[i][f][r];
            }
        }
    }
}

// ---------------- combine: out[t] = sum of t's 4 slot rows ----------------
__global__ __launch_bounds__(256) void combine_kernel(
    const float* __restrict__ ods, const int* __restrict__ tok_slots,
    const int* __restrict__ slot_base, float* __restrict__ out)
{
    const int t = blockIdx.x;
    const int c0 = threadIdx.x * 8;
    const float* rows[TOPK];
#pragma unroll
    for (int r = 0; r < TOPK; ++r) {
        const int pk = tok_slots[t * TOPK + r];
        const int e = pk >> 12, pos = pk & 4095;
        rows[r] = ods + (size_t)(slot_base[e] + pos) * H_DIM + c0;
    }
    float4 a0 = {0.f,0.f,0.f,0.f}, a1 = {0.f,0.f,0.f,0.f};
#pragma unroll
    for (int r = 0; r < TOPK; ++r) {
        float4 v0 = *(const float4*)(rows[r]);
        float4 v1 = *(const float4*)(rows[r] + 4);
        a0.x += v0.x; a0.y += v0.y; a0.z += v0.z; a0.w += v0.w;
        a1.x += v1.x; a1.y += v1.y; a1.z += v1.z; a1.w += v1.w;
    }
    float* o = out + (size_t)t * H_DIM + c0;
    *(float4*)o = a0;
    *(float4*)(o + 4) = a1;
}

extern "C" void kernel_launch(void* const* d_in, const int* in_sizes, int n_in,
                              void* d_out, int out_size, void* d_ws, size_t ws_size,
                              hipStream_t stream) {
    const float* x      = (const float*)d_in[0];
    const float* gate_w = (const float*)d_in[1];
    const float* gup_w  = (const float*)d_in[2];
    const float* down_w = (const float*)d_in[3];
    float* out    = (float*)d_out;

    char* wsp = (char*)d_ws;
    int*   cnt       = (int*)(wsp);
    int*   slot_base = (int*)(wsp + 256);
    int*   tok_list  = (int*)(wsp + 4096);
    float* tok_w     = (float*)(wsp + 4096 + (size_t)E_NUM * T_TOK * 4);
    int*   tok_slots = (int*)(wsp + (768u << 10));

    size_t off = (size_t)1 << 20;
    unsigned short* xg_t = (unsigned short*)(wsp + off); off += (size_t)S4 * H_DIM * 2;  // 33.6MB
    unsigned short* h_t  = (unsigned short*)(wsp + off); off += (size_t)S4 * I_DIM * 2;  // 12.6MB
    float*          ods  = (float*)(wsp + off);          off += (size_t)S4 * H_DIM * 4;  // 67MB

    hipMemsetAsync(cnt, 0, 256, stream);

    router_kernel<<<T_TOK, 64, 0, stream>>>(x, gate_w, out + (size_t)T_TOK * H_DIM,
                                            cnt, tok_list, tok_w, tok_slots);
    scan_kernel<<<1, 64, 0, stream>>>(cnt, slot_base);
    gather_kernel<<<dim3(E_NUM, 256), 256, 0, stream>>>(x, cnt, slot_base, tok_list, xg_t);
    gateup_mfma<<<dim3(E_NUM, 24, 8), 512, 0, stream>>>(
        xg_t, gup_w, cnt, slot_base, tok_w, h_t);
    down_mfma<<<dim3(E_NUM, 32, 8), 512, 0, stream>>>(
        h_t, down_w, cnt, slot_base, ods);
    combine_kernel<<<T_TOK, 256, 0, stream>>>(ods, tok_slots, slot_base, out);
}